// Round 6
// baseline (121.837 us; speedup 1.0000x reference)
//
#include <hip/hip_runtime.h>
#include <math.h>

#define HIDDEN 64
#define WAVE_SAMPLES 512            // samples per wave in phase 1
#define BLOCK_SAMPLES 2048          // samples per block (4 waves)
#define SPAN 4096                   // local first-sample table span (ray ids)
#define MAGIC 0x3A9F17C5u           // slot-ready flag (improbable poison value)

typedef _Float16 half8   __attribute__((ext_vector_type(8)));
typedef _Float16 half2_t __attribute__((ext_vector_type(2)));
typedef float    f32x16  __attribute__((ext_vector_type(16)));
typedef int      int4_t  __attribute__((ext_vector_type(4)));

struct __align__(16) Slot { unsigned s, d, flag, pad; };

// DPP add: v + dpp_perm(v), old=0, bound_ctrl=1.
template <int CTRL, int RMASK>
__device__ __forceinline__ float dpp_add(float v) {
    int t = __builtin_amdgcn_update_dpp(0, __builtin_bit_cast(int, v),
                                        CTRL, RMASK, 0xF, true);
    return v + __builtin_bit_cast(float, t);
}

__device__ __forceinline__ float bcast_lane(float v, int lane) {
    return __builtin_bit_cast(float,
        __builtin_amdgcn_readlane(__builtin_bit_cast(int, v), lane));
}

__device__ __forceinline__ half2_t pack2(float a, float b) {
    return __builtin_bit_cast(half2_t, __builtin_amdgcn_cvt_pkrtz(a, b));
}

__device__ __forceinline__ half2_t pk_relu(half2_t h) {
    half2_t r;
    asm("v_pk_max_f16 %0, %1, 0" : "=v"(r) : "v"(h));
    return r;
}

// full wave64 inclusive scan (6 DPP adds)
__device__ __forceinline__ float scan64(float v) {
    v = dpp_add<0x111, 0xF>(v);
    v = dpp_add<0x112, 0xF>(v);
    v = dpp_add<0x114, 0xF>(v);
    v = dpp_add<0x118, 0xF>(v);
    v = dpp_add<0x142, 0xA>(v);   // row_bcast:15 -> rows 1,3
    v = dpp_add<0x143, 0xC>(v);   // row_bcast:31 -> rows 2,3
    return v;
}

// layer1 MFMA pair (issue only; epilogue separated for prefetch interleave)
__device__ __forceinline__ void mlp_mfma(half8 a0, half8 a1, half8 bf,
                                         f32x16& d0, f32x16& d1) {
    const f32x16 zc = {};
    d0 = __builtin_amdgcn_mfma_f32_32x32x16_f16(a0, bf, zc, 0, 0, 0);
    d1 = __builtin_amdgcn_mfma_f32_32x32x16_f16(a1, bf, zc, 0, 0, 0);
}

// layer2: pack/pk_relu/dot2 over both half-matrices -> per-lane partial
__device__ __forceinline__ float mlp_epi(const f32x16& d0, const f32x16& d1,
                                         const half2_t* w2a, const half2_t* w2b) {
    float c0 = 0.0f, c1 = 0.0f, c2 = 0.0f, c3 = 0.0f;
    #pragma unroll
    for (int r8 = 0; r8 < 8; r8 += 4) {
        c0 = __builtin_amdgcn_fdot2(pk_relu(pack2(d0[2*r8+0], d0[2*r8+1])), w2a[r8+0], c0, false);
        c1 = __builtin_amdgcn_fdot2(pk_relu(pack2(d0[2*r8+2], d0[2*r8+3])), w2a[r8+1], c1, false);
        c2 = __builtin_amdgcn_fdot2(pk_relu(pack2(d0[2*r8+4], d0[2*r8+5])), w2a[r8+2], c2, false);
        c3 = __builtin_amdgcn_fdot2(pk_relu(pack2(d0[2*r8+6], d0[2*r8+7])), w2a[r8+3], c3, false);
    }
    #pragma unroll
    for (int r8 = 0; r8 < 8; r8 += 4) {
        c0 = __builtin_amdgcn_fdot2(pk_relu(pack2(d1[2*r8+0], d1[2*r8+1])), w2b[r8+0], c0, false);
        c1 = __builtin_amdgcn_fdot2(pk_relu(pack2(d1[2*r8+2], d1[2*r8+3])), w2b[r8+1], c1, false);
        c2 = __builtin_amdgcn_fdot2(pk_relu(pack2(d1[2*r8+4], d1[2*r8+5])), w2b[r8+2], c2, false);
        c3 = __builtin_amdgcn_fdot2(pk_relu(pack2(d1[2*r8+6], d1[2*r8+7])), w2b[r8+3], c3, false);
    }
    return (c0 + c1) + (c2 + c3);
}

// render one ray piece from LDS: S = sum of sval, D = sum of w*tm (local
// transmittance). Identical math to the former render_scan_kernel loop.
__device__ __forceinline__ void ray_piece(const int* lds_smp, int s, int e,
                                          int lane, float& S, float& D) {
    float carry = 0.0f, depth_acc = 0.0f;
    for (int bb = s; bb < e; bb += 64) {
        const int  i     = bb + lane;
        const bool valid = (i < e);
        const int  ic    = valid ? i : (e - 1);
        const half2_t v  = __builtin_bit_cast(half2_t, lds_smp[ic]);
        const float   sv = valid ? (float)v[0] : 0.0f;
        const float   tm = (float)v[1];
        const float scan = scan64(sv);
        const float incl = carry + scan;
        const float w    = __expf(sv - incl) - __expf(-incl);   // 0 when sv==0
        depth_acc  = fmaf(w, tm, depth_acc);
        carry     += bcast_lane(scan, 63);
    }
    S = carry;
    D = bcast_lane(scan64(depth_acc), 63);
}

// Fused kernel. Phase 1: MLP density per 2048-sample block -> LDS (packed
// {sval,tm} f16x2) + local first-sample table. Phase 2: per-block ray
// rendering from LDS. A ray spans <=2 adjacent blocks (max ~120 samples),
// so cross-block state is one {S,D} slot with a backward (b <- b-1)
// dependency: deadlock-free under in-order dispatch (block 0 never waits),
// and replay-idempotent (published values deterministic).
__global__ __launch_bounds__(256, 4) void fused_render_kernel(
    const float* __restrict__ rays_o, const float* __restrict__ rays_d,
    const float* __restrict__ W1, const float* __restrict__ b1,
    const float* __restrict__ W2, const float* __restrict__ b2,
    const float* __restrict__ t_starts, const int* __restrict__ ray_indices,
    float* __restrict__ out, Slot* __restrict__ slots,
    int n_samples, int n_rays)
{
    __shared__ int            lds_smp[BLOCK_SAMPLES];
    __shared__ unsigned short lf[SPAN];

    const int tid  = threadIdx.x;
    const int lane = tid & 63;
    const int wv   = tid >> 6;              // wave in block (0..3)
    const int bid  = blockIdx.x;
    const int base_blk = bid * BLOCK_SAMPLES;
    const int n = lane & 31;
    const int q = lane >> 5;

    const int base0 = base_blk + wv * WAVE_SAMPLES;
    const int lim = (base0 + WAVE_SAMPLES < n_samples) ? (base0 + WAVE_SAMPLES) : n_samples;

    // ---- preamble: A fragments + W2 f16 pairs (in-register, proven) ----
    half8 a0 = {}, a1 = {};
    if (q == 0) {
        const int m = n;
        a0[0] = (_Float16)W1[0 * HIDDEN + m];
        a0[1] = (_Float16)W1[1 * HIDDEN + m];
        a0[2] = (_Float16)W1[2 * HIDDEN + m];
        a0[3] = (_Float16)b1[m];
        a1[0] = (_Float16)W1[0 * HIDDEN + 32 + m];
        a1[1] = (_Float16)W1[1 * HIDDEN + 32 + m];
        a1[2] = (_Float16)W1[2 * HIDDEN + 32 + m];
        a1[3] = (_Float16)b1[32 + m];
    }
    half2_t w2a[8], w2b[8];
    #pragma unroll
    for (int r8 = 0; r8 < 8; ++r8) {
        const int row = 2 * (r8 & 1) + 8 * (r8 >> 1) + 4 * q;
        half2_t pa, pb;
        pa[0] = (_Float16)W2[row];      pa[1] = (_Float16)W2[row + 1];
        pb[0] = (_Float16)W2[row + 32]; pb[1] = (_Float16)W2[row + 33];
        w2a[r8] = pa; w2b[r8] = pb;
    }
    const float bias2 = b2[0];
    const int xaddr = (lane ^ 32) << 2;
    const int naddr = n << 2;               // source lane n (set A)

    // ray id at block start (for local first-idx table offsets)
    const int r0w = ray_indices[base_blk];
    // carry for the boundary scatter: ray index of sample base0-1
    int carry_r = (base0 > 0) ? ray_indices[base0 - 1] : -1;

    // ---- pipeline prologue (R4: 3-stage r/t, 2-stage redistribute+gathers) ----
    const int c0i = (base0 + lane < n_samples) ? (base0 + lane) : (n_samples - 1);
    int   r_c = ray_indices[c0i];
    float t_c = t_starts[c0i];
    const int c1i = (base0 + 64 + lane < n_samples) ? (base0 + 64 + lane) : (n_samples - 1);
    int   r_n = ray_indices[c1i];
    float t_n = t_starts[c1i];

    int   ria_c = __builtin_amdgcn_ds_bpermute(naddr, r_c);
    int   rib_c = __builtin_amdgcn_ds_bpermute(naddr | 128, r_c);
    float tma_c = __builtin_bit_cast(float,
        __builtin_amdgcn_ds_bpermute(naddr, __builtin_bit_cast(int, t_c))) + 0.0025f;
    float tmb_c = __builtin_bit_cast(float,
        __builtin_amdgcn_ds_bpermute(naddr | 128, __builtin_bit_cast(int, t_c))) + 0.0025f;

    float dxa = rays_d[3 * ria_c + 0], dya = rays_d[3 * ria_c + 1], dza = rays_d[3 * ria_c + 2];
    float oxa = rays_o[3 * ria_c + 0], oya = rays_o[3 * ria_c + 1], oza = rays_o[3 * ria_c + 2];
    float dxb = rays_d[3 * rib_c + 0], dyb = rays_d[3 * rib_c + 1], dzb = rays_d[3 * rib_c + 2];
    float oxb = rays_o[3 * rib_c + 0], oyb = rays_o[3 * rib_c + 1], ozb = rays_o[3 * rib_c + 2];

    for (int base = base0; base < lim; base += 64) {
        const int  iS = base + lane;
        const bool vS = (iS < n_samples);

        // ---- prefetch r/t for k+2 (3-stage) ----
        const int i2 = iS + 128;
        const int c2 = (i2 < n_samples) ? i2 : (n_samples - 1);
        const int   r_f2 = ray_indices[c2];
        const float t_f2 = t_starts[c2];

        // ---- boundary scatter into the local first-idx table ----
        const int prev_in = __builtin_amdgcn_ds_bpermute(((lane + 63) & 63) << 2, r_c);
        const int prev    = (lane == 0) ? carry_r : prev_in;
        if (vS) {
            for (int rr = prev + 1; rr <= r_c; ++rr) {
                const unsigned off = (unsigned)(rr - r0w);
                if (off < SPAN) lf[off] = (unsigned short)(iS - base_blk);
            }
        }
        carry_r = __builtin_amdgcn_readlane(r_c, 63);

        // ---- positions (iter k) from pipelined regs ----
        const float pxa = fmaf(dxa, tma_c, oxa);
        const float pya = fmaf(dya, tma_c, oya);
        const float pza = fmaf(dza, tma_c, oza);
        const float pxb = fmaf(dxb, tmb_c, oxb);
        const float pyb = fmaf(dyb, tmb_c, oyb);
        const float pzb = fmaf(dzb, tmb_c, ozb);

        const int a01 = __builtin_bit_cast(int, __builtin_amdgcn_cvt_pkrtz(pxa, pya));
        const int a23 = __builtin_bit_cast(int, __builtin_amdgcn_cvt_pkrtz(pza, 1.0f));
        const int b01 = __builtin_bit_cast(int, __builtin_amdgcn_cvt_pkrtz(pxb, pyb));
        const int b23 = __builtin_bit_cast(int, __builtin_amdgcn_cvt_pkrtz(pzb, 1.0f));
        const int4_t bia = {a01, a23, 0, 0};
        const int4_t bib = {b01, b23, 0, 0};

        // ---- MFMA A issue ----
        f32x16 d0a, d1a;
        mlp_mfma(a0, a1, __builtin_bit_cast(half8, bia), d0a, d1a);

        // ---- prefetch block for k+1: redistribute + 12 gathers ----
        const int   ria_n = __builtin_amdgcn_ds_bpermute(naddr, r_n);
        const int   rib_n = __builtin_amdgcn_ds_bpermute(naddr | 128, r_n);
        const float tma_n = __builtin_bit_cast(float,
            __builtin_amdgcn_ds_bpermute(naddr, __builtin_bit_cast(int, t_n))) + 0.0025f;
        const float tmb_n = __builtin_bit_cast(float,
            __builtin_amdgcn_ds_bpermute(naddr | 128, __builtin_bit_cast(int, t_n))) + 0.0025f;
        const float g_dxa = rays_d[3 * ria_n + 0], g_dya = rays_d[3 * ria_n + 1], g_dza = rays_d[3 * ria_n + 2];
        const float g_oxa = rays_o[3 * ria_n + 0], g_oya = rays_o[3 * ria_n + 1], g_oza = rays_o[3 * ria_n + 2];
        const float g_dxb = rays_d[3 * rib_n + 0], g_dyb = rays_d[3 * rib_n + 1], g_dzb = rays_d[3 * rib_n + 2];
        const float g_oxb = rays_o[3 * rib_n + 0], g_oyb = rays_o[3 * rib_n + 1], g_ozb = rays_o[3 * rib_n + 2];

        // ---- epilogue A, MFMA B + epilogue B ----
        const float acc_a = mlp_epi(d0a, d1a, w2a, w2b);
        f32x16 d0b, d1b;
        mlp_mfma(a0, a1, __builtin_bit_cast(half8, bib), d0b, d1b);
        const float acc_b = mlp_epi(d0b, d1b, w2a, w2b);

        // ---- swap-trick: each half finishes only its own set ----
        const float send = q ? acc_a : acc_b;
        const float keep = q ? acc_b : acc_a;
        const float oth  = __builtin_bit_cast(float,
            __builtin_amdgcn_ds_bpermute(xaddr, __builtin_bit_cast(int, send)));
        const float z  = keep + oth + bias2;
        const float sg = fmaxf(z, 0.0f) + __logf(1.0f + __expf(-fabsf(z)));

        if (vS) lds_smp[iS - base_blk] =
            __builtin_bit_cast(int, pack2(sg * 0.005f, t_c + 0.0025f));

        // ---- rotate pipeline regs ----
        r_c = r_n;  t_c = t_n;
        r_n = r_f2; t_n = t_f2;
        ria_c = ria_n; rib_c = rib_n; tma_c = tma_n; tmb_c = tmb_n;
        dxa = g_dxa; dya = g_dya; dza = g_dza;
        oxa = g_oxa; oya = g_oya; oza = g_oza;
        dxb = g_dxb; dyb = g_dyb; dzb = g_dzb;
        oxb = g_oxb; oyb = g_oyb; ozb = g_ozb;
    }

    __syncthreads();

    // ================= phase 2: render rays of this block =================
    const int lastS  = ((base_blk + BLOCK_SAMPLES) < n_samples
                        ? (base_blk + BLOCK_SAMPLES) : n_samples) - 1;
    const int nLocal = lastS - base_blk + 1;
    const int r0     = r0w;
    const int rE     = ray_indices[lastS];
    const int rPrev  = (base_blk > 0) ? ray_indices[base_blk - 1] : -1;
    const bool contL = (rPrev == r0);
    const bool contR = (base_blk + BLOCK_SAMPLES < n_samples) &&
                       (ray_indices[base_blk + BLOCK_SAMPLES] == rE);
    const int kmax   = (rE - (contR ? 1 : 0)) - r0;   // owned rays: r0+k, k in [0,kmax]
    const float tiny = 1.17549435e-38f;

    // publish right-edge piece FIRST (minimizes neighbor wait)
    if (contR && wv == ((rE - r0) & 3)) {
        float S, D;
        ray_piece(lds_smp, lf[rE - r0], nLocal, lane, S, D);
        if (lane == 0) {
            __hip_atomic_store(&slots[bid].s, __builtin_bit_cast(unsigned, S),
                               __ATOMIC_RELAXED, __HIP_MEMORY_SCOPE_AGENT);
            __hip_atomic_store(&slots[bid].d, __builtin_bit_cast(unsigned, D),
                               __ATOMIC_RELAXED, __HIP_MEMORY_SCOPE_AGENT);
            __hip_atomic_store(&slots[bid].flag, MAGIC,
                               __ATOMIC_RELEASE, __HIP_MEMORY_SCOPE_AGENT);
        }
    }

    // owned rays, round-robin across the 4 waves; defer k==0 if left-cut
    for (int k = wv; k <= kmax; k += 4) {
        if (k == 0 && contL) continue;
        const int s = (k == 0) ? 0 : lf[k];
        const int e = (r0 + k == rE) ? nLocal : lf[k + 1];
        float S, D;
        ray_piece(lds_smp, s, e, lane, S, D);
        const float op = 1.0f - __expf(-S);
        if (lane == 0) {
            out[2 * (r0 + k) + 0] = op;
            out[2 * (r0 + k) + 1] = D / fmaxf(op, tiny);
        }
    }

    // left-cut ray: combine local piece with the previous block's published piece
    if (contL && wv == 0) {
        const int e = (r0 == rE) ? nLocal : lf[1];
        float S2, D2;
        ray_piece(lds_smp, 0, e, lane, S2, D2);
        unsigned f;
        do {
            f = __hip_atomic_load(&slots[bid - 1].flag, __ATOMIC_ACQUIRE,
                                  __HIP_MEMORY_SCOPE_AGENT);
            if (f != MAGIC) __builtin_amdgcn_s_sleep(2);
        } while (f != MAGIC);
        const float S1 = __builtin_bit_cast(float,
            __hip_atomic_load(&slots[bid - 1].s, __ATOMIC_RELAXED, __HIP_MEMORY_SCOPE_AGENT));
        const float D1 = __builtin_bit_cast(float,
            __hip_atomic_load(&slots[bid - 1].d, __ATOMIC_RELAXED, __HIP_MEMORY_SCOPE_AGENT));
        const float S  = S1 + S2;
        const float D  = D1 + __expf(-S1) * D2;
        const float op = 1.0f - __expf(-S);
        if (lane == 0) {
            out[2 * r0 + 0] = op;
            out[2 * r0 + 1] = D / fmaxf(op, tiny);
        }
    }

    // empty rays skipped across the left block boundary
    for (int r = rPrev + 1 + tid; r < r0; r += 256) {
        out[2 * r + 0] = 0.0f; out[2 * r + 1] = 0.0f;
    }
    // trailing empty rays (last block only)
    if (base_blk + BLOCK_SAMPLES >= n_samples) {
        for (int r = rE + 1 + tid; r < n_rays; r += 256) {
            out[2 * r + 0] = 0.0f; out[2 * r + 1] = 0.0f;
        }
    }
}

extern "C" void kernel_launch(void* const* d_in, const int* in_sizes, int n_in,
                              void* d_out, int out_size, void* d_ws, size_t ws_size,
                              hipStream_t stream) {
    const float* rays_o      = (const float*)d_in[0];
    const float* rays_d      = (const float*)d_in[1];
    const float* W1          = (const float*)d_in[2];
    const float* b1          = (const float*)d_in[3];
    const float* W2          = (const float*)d_in[4];
    const float* b2          = (const float*)d_in[5];
    const float* t_starts    = (const float*)d_in[6];
    const int*   ray_indices = (const int*)d_in[8];

    const int n_rays    = in_sizes[0] / 3;
    const int n_samples = in_sizes[6];

    float* out  = (float*)d_out;
    Slot* slots = (Slot*)d_ws;      // one 16-B slot per block

    const int blocks = (n_samples + BLOCK_SAMPLES - 1) / BLOCK_SAMPLES;  // 1024
    fused_render_kernel<<<blocks, 256, 0, stream>>>(
        rays_o, rays_d, W1, b1, W2, b2, t_starts, ray_indices,
        out, slots, n_samples, n_rays);
}

// Round 7
// 108.359 us; speedup vs baseline: 1.1244x; 1.1244x over previous
//
#include <hip/hip_runtime.h>
#include <math.h>

#define HIDDEN 64
#define WAVE_SAMPLES 512          // samples per wave in the dense MLP kernel
#define SVAL_OFFSET 262144        // byte offset of packed {sval,tm} f16x2[] in d_ws

typedef _Float16 half8   __attribute__((ext_vector_type(8)));
typedef _Float16 half2_t __attribute__((ext_vector_type(2)));
typedef float    f32x16  __attribute__((ext_vector_type(16)));
typedef int      int4_t  __attribute__((ext_vector_type(4)));

// DPP add: v + dpp_perm(v), old=0, bound_ctrl=1.
template <int CTRL, int RMASK>
__device__ __forceinline__ float dpp_add(float v) {
    int t = __builtin_amdgcn_update_dpp(0, __builtin_bit_cast(int, v),
                                        CTRL, RMASK, 0xF, true);
    return v + __builtin_bit_cast(float, t);
}

__device__ __forceinline__ float bcast_lane(float v, int lane) {
    return __builtin_bit_cast(float,
        __builtin_amdgcn_readlane(__builtin_bit_cast(int, v), lane));
}

__device__ __forceinline__ half2_t pack2(float a, float b) {
    return __builtin_bit_cast(half2_t, __builtin_amdgcn_cvt_pkrtz(a, b));
}

__device__ __forceinline__ half2_t pk_relu(half2_t h) {
    half2_t r;
    asm("v_pk_max_f16 %0, %1, 0" : "=v"(r) : "v"(h));
    return r;
}

// full wave64 inclusive scan (6 DPP adds)
__device__ __forceinline__ float scan64(float v) {
    v = dpp_add<0x111, 0xF>(v);
    v = dpp_add<0x112, 0xF>(v);
    v = dpp_add<0x114, 0xF>(v);
    v = dpp_add<0x118, 0xF>(v);
    v = dpp_add<0x142, 0xA>(v);   // row_bcast:15 -> rows 1,3
    v = dpp_add<0x143, 0xC>(v);   // row_bcast:31 -> rows 2,3
    return v;
}

// layer1 MFMA pair (issue only; epilogue separated for prefetch interleave)
__device__ __forceinline__ void mlp_mfma(half8 a0, half8 a1, half8 bf,
                                         f32x16& d0, f32x16& d1) {
    const f32x16 zc = {};
    d0 = __builtin_amdgcn_mfma_f32_32x32x16_f16(a0, bf, zc, 0, 0, 0);
    d1 = __builtin_amdgcn_mfma_f32_32x32x16_f16(a1, bf, zc, 0, 0, 0);
}

// layer2: pack/pk_relu/dot2 over both half-matrices -> per-lane partial
__device__ __forceinline__ float mlp_epi(const f32x16& d0, const f32x16& d1,
                                         const half2_t* w2a, const half2_t* w2b) {
    float c0 = 0.0f, c1 = 0.0f, c2 = 0.0f, c3 = 0.0f;
    #pragma unroll
    for (int r8 = 0; r8 < 8; r8 += 4) {
        c0 = __builtin_amdgcn_fdot2(pk_relu(pack2(d0[2*r8+0], d0[2*r8+1])), w2a[r8+0], c0, false);
        c1 = __builtin_amdgcn_fdot2(pk_relu(pack2(d0[2*r8+2], d0[2*r8+3])), w2a[r8+1], c1, false);
        c2 = __builtin_amdgcn_fdot2(pk_relu(pack2(d0[2*r8+4], d0[2*r8+5])), w2a[r8+2], c2, false);
        c3 = __builtin_amdgcn_fdot2(pk_relu(pack2(d0[2*r8+6], d0[2*r8+7])), w2a[r8+3], c3, false);
    }
    #pragma unroll
    for (int r8 = 0; r8 < 8; r8 += 4) {
        c0 = __builtin_amdgcn_fdot2(pk_relu(pack2(d1[2*r8+0], d1[2*r8+1])), w2b[r8+0], c0, false);
        c1 = __builtin_amdgcn_fdot2(pk_relu(pack2(d1[2*r8+2], d1[2*r8+3])), w2b[r8+1], c1, false);
        c2 = __builtin_amdgcn_fdot2(pk_relu(pack2(d1[2*r8+4], d1[2*r8+5])), w2b[r8+2], c2, false);
        c3 = __builtin_amdgcn_fdot2(pk_relu(pack2(d1[2*r8+6], d1[2*r8+7])), w2b[r8+3], c3, false);
    }
    return (c0 + c1) + (c2 + c3);
}

// Kernel 1 (dense, sample-parallel). R4 pipeline; R5: bmask ANDs removed —
// A-operand regs for k=8..15 (q=1 lanes) are zero, so B's k>=8 values are
// multiplied by 0 regardless (all inputs finite => no NaN). Identical math.
// R7: exact revert to the R5 best (fusion regressed: VGPR/occupancy cliff).
__global__ __launch_bounds__(256, 4) void mlp_density_kernel(
    const float* __restrict__ rays_o, const float* __restrict__ rays_d,
    const float* __restrict__ W1, const float* __restrict__ b1,
    const float* __restrict__ W2, const float* __restrict__ b2,
    const float* __restrict__ t_starts, const int* __restrict__ ray_indices,
    int* __restrict__ smp_out, int* __restrict__ first_idx,
    int n_samples, int n_rays)
{
    const int tid  = threadIdx.x;
    const int lane = tid & 63;
    const int wave = (blockIdx.x * blockDim.x + tid) >> 6;
    const int n = lane & 31;
    const int q = lane >> 5;

    const int base0 = wave * WAVE_SAMPLES;
    if (base0 >= n_samples) return;
    const int lim = (base0 + WAVE_SAMPLES < n_samples) ? (base0 + WAVE_SAMPLES) : n_samples;

    // ---- preamble: A fragments + W2 f16 pairs (in-register, proven) ----
    half8 a0 = {}, a1 = {};
    if (q == 0) {
        const int m = n;
        a0[0] = (_Float16)W1[0 * HIDDEN + m];
        a0[1] = (_Float16)W1[1 * HIDDEN + m];
        a0[2] = (_Float16)W1[2 * HIDDEN + m];
        a0[3] = (_Float16)b1[m];
        a1[0] = (_Float16)W1[0 * HIDDEN + 32 + m];
        a1[1] = (_Float16)W1[1 * HIDDEN + 32 + m];
        a1[2] = (_Float16)W1[2 * HIDDEN + 32 + m];
        a1[3] = (_Float16)b1[32 + m];
    }
    half2_t w2a[8], w2b[8];
    #pragma unroll
    for (int r8 = 0; r8 < 8; ++r8) {
        const int row = 2 * (r8 & 1) + 8 * (r8 >> 1) + 4 * q;
        half2_t pa, pb;
        pa[0] = (_Float16)W2[row];      pa[1] = (_Float16)W2[row + 1];
        pb[0] = (_Float16)W2[row + 32]; pb[1] = (_Float16)W2[row + 33];
        w2a[r8] = pa; w2b[r8] = pb;
    }
    const float bias2 = b2[0];
    const int xaddr = (lane ^ 32) << 2;
    const int naddr = n << 2;               // source lane n (set A)

    // carry for first_idx scatter: ray index of sample base0-1
    int carry_r = (base0 > 0) ? ray_indices[base0 - 1] : -1;

    // ---- pipeline prologue ----
    const int c0i = (base0 + lane < n_samples) ? (base0 + lane) : (n_samples - 1);
    int   r_c = ray_indices[c0i];
    float t_c = t_starts[c0i];
    const int c1i = (base0 + 64 + lane < n_samples) ? (base0 + 64 + lane) : (n_samples - 1);
    int   r_n = ray_indices[c1i];
    float t_n = t_starts[c1i];

    int   ria_c = __builtin_amdgcn_ds_bpermute(naddr, r_c);
    int   rib_c = __builtin_amdgcn_ds_bpermute(naddr | 128, r_c);
    float tma_c = __builtin_bit_cast(float,
        __builtin_amdgcn_ds_bpermute(naddr, __builtin_bit_cast(int, t_c))) + 0.0025f;
    float tmb_c = __builtin_bit_cast(float,
        __builtin_amdgcn_ds_bpermute(naddr | 128, __builtin_bit_cast(int, t_c))) + 0.0025f;

    float dxa = rays_d[3 * ria_c + 0], dya = rays_d[3 * ria_c + 1], dza = rays_d[3 * ria_c + 2];
    float oxa = rays_o[3 * ria_c + 0], oya = rays_o[3 * ria_c + 1], oza = rays_o[3 * ria_c + 2];
    float dxb = rays_d[3 * rib_c + 0], dyb = rays_d[3 * rib_c + 1], dzb = rays_d[3 * rib_c + 2];
    float oxb = rays_o[3 * rib_c + 0], oyb = rays_o[3 * rib_c + 1], ozb = rays_o[3 * rib_c + 2];

    for (int base = base0; base < lim; base += 64) {
        const int  iS = base + lane;
        const bool vS = (iS < n_samples);

        // ---- prefetch r/t for k+2 (3-stage) ----
        const int i2 = iS + 128;
        const int c2 = (i2 < n_samples) ? i2 : (n_samples - 1);
        const int   r_f2 = ray_indices[c2];
        const float t_f2 = t_starts[c2];

        // ---- fused first_idx scatter (iter k) ----
        const int prev_in = __builtin_amdgcn_ds_bpermute(((lane + 63) & 63) << 2, r_c);
        const int prev    = (lane == 0) ? carry_r : prev_in;
        if (vS) {
            for (int r = prev + 1; r <= r_c; ++r) first_idx[r] = iS;
            if (iS == n_samples - 1) {
                for (int r = r_c + 1; r < n_rays; ++r) first_idx[r] = n_samples;
            }
        }
        carry_r = __builtin_amdgcn_readlane(r_c, 63);

        // ---- positions (iter k) from pipelined regs ----
        const float pxa = fmaf(dxa, tma_c, oxa);
        const float pya = fmaf(dya, tma_c, oya);
        const float pza = fmaf(dza, tma_c, oza);
        const float pxb = fmaf(dxb, tmb_c, oxb);
        const float pyb = fmaf(dyb, tmb_c, oyb);
        const float pzb = fmaf(dzb, tmb_c, ozb);

        const int a01 = __builtin_bit_cast(int, __builtin_amdgcn_cvt_pkrtz(pxa, pya));
        const int a23 = __builtin_bit_cast(int, __builtin_amdgcn_cvt_pkrtz(pza, 1.0f));
        const int b01 = __builtin_bit_cast(int, __builtin_amdgcn_cvt_pkrtz(pxb, pyb));
        const int b23 = __builtin_bit_cast(int, __builtin_amdgcn_cvt_pkrtz(pzb, 1.0f));
        const int4_t bia = {a01, a23, 0, 0};
        const int4_t bib = {b01, b23, 0, 0};

        // ---- MFMA A issue ----
        f32x16 d0a, d1a;
        mlp_mfma(a0, a1, __builtin_bit_cast(half8, bia), d0a, d1a);

        // ---- prefetch block for k+1: redistribute + 12 gathers ----
        const int   ria_n = __builtin_amdgcn_ds_bpermute(naddr, r_n);
        const int   rib_n = __builtin_amdgcn_ds_bpermute(naddr | 128, r_n);
        const float tma_n = __builtin_bit_cast(float,
            __builtin_amdgcn_ds_bpermute(naddr, __builtin_bit_cast(int, t_n))) + 0.0025f;
        const float tmb_n = __builtin_bit_cast(float,
            __builtin_amdgcn_ds_bpermute(naddr | 128, __builtin_bit_cast(int, t_n))) + 0.0025f;
        const float g_dxa = rays_d[3 * ria_n + 0], g_dya = rays_d[3 * ria_n + 1], g_dza = rays_d[3 * ria_n + 2];
        const float g_oxa = rays_o[3 * ria_n + 0], g_oya = rays_o[3 * ria_n + 1], g_oza = rays_o[3 * ria_n + 2];
        const float g_dxb = rays_d[3 * rib_n + 0], g_dyb = rays_d[3 * rib_n + 1], g_dzb = rays_d[3 * rib_n + 2];
        const float g_oxb = rays_o[3 * rib_n + 0], g_oyb = rays_o[3 * rib_n + 1], g_ozb = rays_o[3 * rib_n + 2];

        // ---- epilogue A, MFMA B + epilogue B ----
        const float acc_a = mlp_epi(d0a, d1a, w2a, w2b);
        f32x16 d0b, d1b;
        mlp_mfma(a0, a1, __builtin_bit_cast(half8, bib), d0b, d1b);
        const float acc_b = mlp_epi(d0b, d1b, w2a, w2b);

        // ---- swap-trick: each half finishes only its own set ----
        const float send = q ? acc_a : acc_b;
        const float keep = q ? acc_b : acc_a;
        const float oth  = __builtin_bit_cast(float,
            __builtin_amdgcn_ds_bpermute(xaddr, __builtin_bit_cast(int, send)));
        const float z  = keep + oth + bias2;
        const float sg = fmaxf(z, 0.0f) + __logf(1.0f + __expf(-fabsf(z)));

        if (vS) smp_out[iS] = __builtin_bit_cast(int, pack2(sg * 0.005f, t_c + 0.0025f));

        // ---- rotate pipeline regs ----
        r_c = r_n;  t_c = t_n;
        r_n = r_f2; t_n = t_f2;
        ria_c = ria_n; rib_c = rib_n; tma_c = tma_n; tmb_c = tmb_n;
        dxa = g_dxa; dya = g_dya; dza = g_dza;
        oxa = g_oxa; oya = g_oya; oza = g_oza;
        dxb = g_dxb; dyb = g_dyb; dzb = g_dzb;
        oxb = g_oxb; oyb = g_oyb; ozb = g_ozb;
    }
}

// Kernel 2 (light): one wave64 per ray, lane = sample. R5: telescoped
// opacity — w_i = e^{-excl_i} - e^{-incl_i} telescopes, so
// opacity = 1 - exp(-sum(s)) with the sum already in `carry`. Removes the
// op_acc accumulate and one full scan64 (~20% of k2 issue).
__global__ __launch_bounds__(256, 8) void render_scan_kernel(
    const int* __restrict__ smp, const int* __restrict__ first_idx,
    float* __restrict__ out, int n_rays, int n_samples)
{
    const int tid  = threadIdx.x;
    const int lane = tid & 63;
    const int ray  = (blockIdx.x * blockDim.x + tid) >> 6;
    if (ray >= n_rays) return;

    const int seg_start = first_idx[ray];
    const int seg_end   = (ray + 1 < n_rays) ? first_idx[ray + 1] : n_samples;
    if (seg_start >= seg_end) {
        if (lane == 0) { out[2 * ray] = 0.0f; out[2 * ray + 1] = 0.0f; }
        return;
    }

    float carry = 0.0f, depth_acc = 0.0f;
    const int last = seg_end - 1;

    for (int base = seg_start; base < seg_end; base += 64) {
        const int  i     = base + lane;
        const bool valid = (i < seg_end);
        const int  ic    = valid ? i : last;

        const half2_t v  = __builtin_bit_cast(half2_t, smp[ic]);
        const float   sv = valid ? (float)v[0] : 0.0f;
        const float   tm = (float)v[1];

        const float scan = scan64(sv);
        const float incl = carry + scan;
        const float w    = __expf(sv - incl) - __expf(-incl);   // 0 when sv==0

        depth_acc  = fmaf(w, tm, depth_acc);
        carry     += bcast_lane(scan, 63);
    }

    // telescoped: sum_i w_i = e^{-0} - e^{-total} = 1 - exp(-carry)
    const float op_tot = 1.0f - __expf(-carry);
    const float dp_tot = bcast_lane(scan64(depth_acc), 63);

    if (lane == 0) {
        const float tiny = 1.17549435e-38f;
        out[2 * ray + 0] = op_tot;
        out[2 * ray + 1] = dp_tot / fmaxf(op_tot, tiny);
    }
}

extern "C" void kernel_launch(void* const* d_in, const int* in_sizes, int n_in,
                              void* d_out, int out_size, void* d_ws, size_t ws_size,
                              hipStream_t stream) {
    const float* rays_o      = (const float*)d_in[0];
    const float* rays_d      = (const float*)d_in[1];
    const float* W1          = (const float*)d_in[2];
    const float* b1          = (const float*)d_in[3];
    const float* W2          = (const float*)d_in[4];
    const float* b2          = (const float*)d_in[5];
    const float* t_starts    = (const float*)d_in[6];
    const int*   ray_indices = (const int*)d_in[8];

    const int n_rays    = in_sizes[0] / 3;
    const int n_samples = in_sizes[6];

    float* out       = (float*)d_out;
    int*   first_idx = (int*)d_ws;                            // n_rays ints
    int*   smp       = (int*)((char*)d_ws + SVAL_OFFSET);     // n_samples words

    {
        const int waves  = (n_samples + WAVE_SAMPLES - 1) / WAVE_SAMPLES;
        const int blocks = (waves + 3) / 4;                   // 4 waves/block
        mlp_density_kernel<<<blocks, 256, 0, stream>>>(
            rays_o, rays_d, W1, b1, W2, b2, t_starts, ray_indices,
            smp, first_idx, n_samples, n_rays);
    }
    {
        const int blocks = (n_rays * 64 + 255) / 256;         // 1 wave/ray
        render_scan_kernel<<<blocks, 256, 0, stream>>>(
            smp, first_idx, out, n_rays, n_samples);
    }
}